// Round 15
// baseline (254.118 us; speedup 1.0000x reference)
//
#include <hip/hip_runtime.h>

// emb lookup -> RNN tanh(xp_t + h @ W_hh^T) over S=128 -> 5-class head.
// B=4096, S=128, D=256, VOCAB=50000. Floats f32, x int32, out f32.
//
// R21: the fused kernel (R15: ALL work in 197.8us in-kernel) with a grid
// barrier that avoids both measured failure modes:
//   R12 acquire-scope POLL: correct but every poll = L2 invalidate -> 256
//       spinners poisoned all XCD L2s (294us whole-kernel dilation).
//   R13 relaxed plain-LOAD poll: hang — the load is served forever from the
//       spinner's own XCD L2; remote RMWs never invalidate it.
// Fix: poll with a RELAXED atomic RMW (fetch_add(&g_done, 0)) — RMWs execute
// at the coherence point (cross-XCD RMW coherence PROVEN by R12's g_arrive
// epoch arithmetic working every replay), and relaxed ordering emits no cache
// maintenance. ONE acquire load at exit (single invalidate, covers the CU's
// shared L1/L2) + __syncthreads. Release side = R12's (passed correctness).
// s_sleep(32) ~0.85us backoff keeps same-line RMW contention trivial.
// Epoch targets (old & ~255)+256 survive graph replays without reset.
// Deadlock-safe: 256 blocks co-reside (R12 confirmed empirically).
//
// Phase A: 8 waves x 2 col-tiles, dbuf tin, 2-tile reg prefetch, lgkm-only
// barrier, direct g_P stores (~62us measured in R15). Phase C: R6 rnn body
// (depth-4 gather pipeline, granule-XOR-swizzled h LDS, ~136us in R15).
// Both bodies verbatim from R12 (passed, absmax 0.0078125).

typedef __attribute__((ext_vector_type(8))) short bf16x8;   // 8 bf16 = 4 VGPRs
typedef __attribute__((ext_vector_type(4))) float f32x4;    // MFMA 16x16 accumulator

#define VOCAB 50000
#define LDS_STRIDE 264   // phase A staging stride (ushorts)

__device__ __align__(256) unsigned short g_P[VOCAB * 256];  // 25.6 MB projected table
__device__ unsigned int g_arrive = 0;   // monotone across graph replays
__device__ unsigned int g_done   = 0;

static __device__ __forceinline__ float bf2f(unsigned short u) {
    union { unsigned int i; float f; } v; v.i = ((unsigned int)u) << 16; return v.f;
}
static __device__ __forceinline__ float bfbits2f(unsigned int zext_u16) {
    union { unsigned int i; float f; } v; v.i = zext_u16 << 16; return v.f;
}
static __device__ __forceinline__ unsigned short f2bf_rne(float f) {
    union { float f; unsigned int i; } v; v.f = f;
    unsigned int r = v.i + 0x7FFFu + ((v.i >> 16) & 1u);
    return (unsigned short)(r >> 16);
}
static __device__ __forceinline__ unsigned short f2bf_fast(float f) {   // round-half-up
    union { float f; unsigned int i; } v; v.f = f;
    return (unsigned short)((v.i + 0x8000u) >> 16);
}
static __device__ __forceinline__ bf16x8 cvt8(float4 a, float4 b) {
    bf16x8 r;
    r[0] = (short)f2bf_rne(a.x); r[1] = (short)f2bf_rne(a.y);
    r[2] = (short)f2bf_rne(a.z); r[3] = (short)f2bf_rne(a.w);
    r[4] = (short)f2bf_rne(b.x); r[5] = (short)f2bf_rne(b.y);
    r[6] = (short)f2bf_rne(b.z); r[7] = (short)f2bf_rne(b.w);
    return r;
}
static __device__ __forceinline__ bf16x8 load8_bf(const float* __restrict__ p) {
    return cvt8(((const float4*)p)[0], ((const float4*)p)[1]);
}
// tanh(x) = 1 - 2/(e^{2x}+1); med3 clamp keeps exp finite
static __device__ __forceinline__ float fast_tanh(float x) {
    x = __builtin_amdgcn_fmed3f(x, -8.f, 8.f);
    float e = __expf(2.f * x);
    return __builtin_fmaf(-2.f, __builtin_amdgcn_rcpf(e + 1.f), 1.f);
}
// Workgroup barrier that does NOT drain vmcnt: only LDS ops must be visible.
static __device__ __forceinline__ void barrier_lds_only() {
    asm volatile("s_waitcnt lgkmcnt(0)\n\ts_barrier" ::: "memory");
}

// ---------------- fused: projection -> device-atomic grid barrier -> recurrence ----------------
__global__ __launch_bounds__(512, 2)
void rnn_fused_kernel(const int* __restrict__ x,
                      const float* __restrict__ emb,
                      const float* __restrict__ W_ih,
                      const float* __restrict__ W_hh,
                      const float* __restrict__ b_ih,
                      const float* __restrict__ b_hh,
                      const float* __restrict__ W_cls,
                      const float* __restrict__ b_cls,
                      float* __restrict__ out)
{
    __shared__ __align__(16) unsigned short tin[2][16 * LDS_STRIDE];  // 16.9 KB (phase A)
    __shared__ __align__(16) unsigned short h_lds[2][16 * 256];       // 16 KB
    __shared__ __align__(16) int tok_t[128 * 16];                     // 8 KB
    __shared__ __align__(16) float wcls_lds[5 * 256];                 // 5 KB
    __shared__ float bcls_lds[5];
    __shared__ unsigned int sync_tgt;

    const int tid  = threadIdx.x;
    const int lane = tid & 63;
    const int wid  = tid >> 6;          // 8 waves
    const int b    = blockIdx.x;        // 256 blocks
    const int b0   = b * 16;
    const int n0   = wid * 32;          // wave's 32-col slice (both phases)
    const int l15  = lane & 15;
    const int quad = lane >> 4;

    // barrier epoch: one dispatch's 256 olds span exactly [256k, 256k+256)
    if (tid == 0) {
        unsigned int old = atomicAdd(&g_arrive, 1u);
        sync_tgt = (old & ~255u) + 256u;
    }

    // ---- staging that overlaps phase A (all LDS; visible after barriers) ----
    {   // tokens transposed: tok_t[t*16 + row]
        int row = tid & 15, tq = tid >> 4;   // tq 0..31
        int4 v = *(const int4*)(x + (size_t)(b0 + row) * 128 + tq * 4);
        tok_t[(tq * 4 + 0) * 16 + row] = v.x;
        tok_t[(tq * 4 + 1) * 16 + row] = v.y;
        tok_t[(tq * 4 + 2) * 16 + row] = v.z;
        tok_t[(tq * 4 + 3) * 16 + row] = v.w;
    }
    if (tid < 320) ((float4*)wcls_lds)[tid] = ((const float4*)W_cls)[tid];
    if (tid < 5)   bcls_lds[tid] = b_cls[tid];
    #pragma unroll
    for (int i = 0; i < 4; ++i) ((unsigned int*)h_lds[0])[tid + i * 512] = 0;

    // ================= Phase A: P = bf16(emb @ W_ih^T + (b_ih + b_hh)) =================
    {
        bf16x8 wfA[2][8];
        float  biasA[2];
        #pragma unroll
        for (int nt = 0; nt < 2; ++nt) {
            int n = n0 + nt * 16 + l15;
            biasA[nt] = b_ih[n] + b_hh[n];
            #pragma unroll
            for (int kt = 0; kt < 8; ++kt)
                wfA[nt][kt] = load8_bf(W_ih + n * 256 + quad * 8 + kt * 32);
        }

        const int srow = tid >> 5, sseg = tid & 31;   // staging map: 16 rows x 32 segs x 8 floats
        float4 p0a, p0b, p1a, p1b;                     // 2-tile register prefetch (static names)
        {
            const float4* s0 = (const float4*)(emb + ((size_t)b * 16 + srow) * 256 + sseg * 8);
            p0a = s0[0]; p0b = s0[1];
            int t1 = b + 256;
            if (t1 < 3125) {
                const float4* s1 = (const float4*)(emb + ((size_t)t1 * 16 + srow) * 256 + sseg * 8);
                p1a = s1[0]; p1b = s1[1];
            }
        }

        #define PROJ_STEP(I, PA, PB, TBUF)                                                 \
        {                                                                                  \
            int tile = b + (I) * 256;                                                      \
            if (tile < 3125) {                                                             \
                *(bf16x8*)(&TBUF[srow * LDS_STRIDE + sseg * 8]) = cvt8(PA, PB);            \
                int tf = tile + 512;                                                       \
                if (tf < 3125) {                                                           \
                    const float4* s = (const float4*)(emb + ((size_t)tf * 16 + srow) * 256 + sseg * 8); \
                    PA = s[0]; PB = s[1];                                                  \
                }                                                                          \
                barrier_lds_only();                                                        \
                f32x4 acc0 = (f32x4){0.f, 0.f, 0.f, 0.f};                                  \
                f32x4 acc1 = (f32x4){0.f, 0.f, 0.f, 0.f};                                  \
                _Pragma("unroll")                                                          \
                for (int kt = 0; kt < 8; ++kt) {                                           \
                    bf16x8 a = *(bf16x8*)(&TBUF[l15 * LDS_STRIDE + quad * 8 + kt * 32]);   \
                    acc0 = __builtin_amdgcn_mfma_f32_16x16x32_bf16(a, wfA[0][kt], acc0, 0, 0, 0); \
                    acc1 = __builtin_amdgcn_mfma_f32_16x16x32_bf16(a, wfA[1][kt], acc1, 0, 0, 0); \
                }                                                                          \
                unsigned short* prow = g_P + ((size_t)tile * 16 + quad * 4) * 256 + n0;    \
                _Pragma("unroll")                                                          \
                for (int r = 0; r < 4; ++r) {                                              \
                    prow[r * 256 + l15]      = f2bf_rne(acc0[r] + biasA[0]);               \
                    prow[r * 256 + 16 + l15] = f2bf_rne(acc1[r] + biasA[1]);               \
                }                                                                          \
            }                                                                              \
        }

        #pragma unroll 1
        for (int i2 = 0; i2 < 7; ++i2) {
            PROJ_STEP(2 * i2,     p0a, p0b, tin[0]);
            PROJ_STEP(2 * i2 + 1, p1a, p1b, tin[1]);
        }
        #undef PROJ_STEP
    }

    // ===== grid barrier: release add / relaxed-RMW poll / one acquire =====
    __syncthreads();    // compiler drains vmcnt(0): every wave's g_P stores at L2
    if (tid == 0) {
        // ONE release op per block: writes back this XCD's L2 (covers block's stores)
        __hip_atomic_fetch_add(&g_done, 1u, __ATOMIC_RELEASE, __HIP_MEMORY_SCOPE_AGENT);
        // poll with relaxed RMW: executes at the coherence point (always fresh,
        // R12's g_arrive proved cross-XCD RMW coherence), NO cache maintenance
        while (__hip_atomic_fetch_add(&g_done, 0u, __ATOMIC_RELAXED, __HIP_MEMORY_SCOPE_AGENT) < sync_tgt)
            __builtin_amdgcn_s_sleep(32);
        // ONE acquire: single invalidate so this CU sees fresh g_P
        (void)__hip_atomic_load(&g_done, __ATOMIC_ACQUIRE, __HIP_MEMORY_SCOPE_AGENT);
    }
    __syncthreads();

    // ================= Phase C: recurrence + classifier (R6 body) =================
    bf16x8 wfh[2][8];
    #pragma unroll
    for (int nt = 0; nt < 2; ++nt) {
        int n = n0 + nt * 16 + l15;
        #pragma unroll
        for (int kt = 0; kt < 8; ++kt)
            wfh[nt][kt] = load8_bf(W_hh + n * 256 + quad * 8 + kt * 32);
    }

    int aoff[8];
    #pragma unroll
    for (int kt = 0; kt < 8; ++kt)
        aoff[kt] = l15 * 512 + (((quad + 4 * kt) ^ l15) << 4);
    int woff[8];   // [nt*4 + r]
    #pragma unroll
    for (int nt = 0; nt < 2; ++nt)
        #pragma unroll
        for (int r = 0; r < 4; ++r) {
            int row = quad * 4 + r;
            int g   = (n0 >> 3) + nt * 2 + (l15 >> 3);
            woff[nt * 4 + r] = row * 512 + ((g ^ row) << 4) + (l15 & 7) * 2;
        }

    const unsigned int colByte = (unsigned int)(n0 + l15) * 2;   // within a g_P row

    // prologue: gather xp(t=0..3) -> gA..gD (4-step-deep pipeline)
    unsigned int gA[8], gB[8], gC[8], gD[8];
    #pragma unroll
    for (int r = 0; r < 4; ++r) {
        const int* xr = x + (size_t)(b0 + quad * 4 + r) * 128;
        const unsigned short* p0 = g_P + (size_t)xr[0] * 256 + n0 + l15;
        const unsigned short* p1 = g_P + (size_t)xr[1] * 256 + n0 + l15;
        const unsigned short* p2 = g_P + (size_t)xr[2] * 256 + n0 + l15;
        const unsigned short* p3 = g_P + (size_t)xr[3] * 256 + n0 + l15;
        gA[r] = p0[0]; gA[4 + r] = p0[16];
        gB[r] = p1[0]; gB[4 + r] = p1[16];
        gC[r] = p2[0]; gC[4 + r] = p2[16];
        gD[r] = p3[0]; gD[4 + r] = p3[16];
    }
    barrier_lds_only();

    char* const h0 = (char*)&h_lds[0][0];

    auto step = [&](const char* hA, char* hW, unsigned int* g, int t) {
        f32x4 acc0 = { bfbits2f(g[0]), bfbits2f(g[1]), bfbits2f(g[2]), bfbits2f(g[3]) };
        f32x4 acc1 = { bfbits2f(g[4]), bfbits2f(g[5]), bfbits2f(g[6]), bfbits2f(g[7]) };
        if (t + 4 < 128) {
            int4 tk = *(const int4*)&tok_t[(t + 4) * 16 + quad * 4];
            const unsigned short* r0 = (const unsigned short*)((const char*)g_P + ((unsigned int)tk.x * 512 + colByte));
            const unsigned short* r1 = (const unsigned short*)((const char*)g_P + ((unsigned int)tk.y * 512 + colByte));
            const unsigned short* r2 = (const unsigned short*)((const char*)g_P + ((unsigned int)tk.z * 512 + colByte));
            const unsigned short* r3 = (const unsigned short*)((const char*)g_P + ((unsigned int)tk.w * 512 + colByte));
            g[0] = r0[0]; g[4] = r0[16];
            g[1] = r1[0]; g[5] = r1[16];
            g[2] = r2[0]; g[6] = r2[16];
            g[3] = r3[0]; g[7] = r3[16];
        }
        #pragma unroll
        for (int kt = 0; kt < 8; ++kt) {
            bf16x8 a = *(const bf16x8*)(hA + aoff[kt]);
            acc0 = __builtin_amdgcn_mfma_f32_16x16x32_bf16(a, wfh[0][kt], acc0, 0, 0, 0);
            acc1 = __builtin_amdgcn_mfma_f32_16x16x32_bf16(a, wfh[1][kt], acc1, 0, 0, 0);
        }
        #pragma unroll
        for (int r = 0; r < 4; ++r) {
            *(unsigned short*)(hW + woff[r])     = f2bf_fast(fast_tanh(acc0[r]));
            *(unsigned short*)(hW + woff[4 + r]) = f2bf_fast(fast_tanh(acc1[r]));
        }
    };

    #pragma unroll 1
    for (int t4 = 0; t4 < 32; ++t4) {
        step(h0,        h0 + 8192, gA, 4 * t4);
        barrier_lds_only();
        step(h0 + 8192, h0,        gB, 4 * t4 + 1);
        barrier_lds_only();
        step(h0,        h0 + 8192, gC, 4 * t4 + 2);
        barrier_lds_only();
        step(h0 + 8192, h0,        gD, 4 * t4 + 3);
        barrier_lds_only();
    }

    // final h in buf0. Classifier: 4 threads per (row,c), shuffle-reduce.
    if (tid < 320) {
        int q = tid & 3, p = tid >> 2;
        int row = p / 5, c = p - row * 5;
        float acc = 0.f;
        #pragma unroll
        for (int kk = 0; kk < 64; ++kk) {
            int k = q * 64 + kk;
            int off = row * 512 + ((((k >> 3) ^ row)) << 4) + (k & 7) * 2;
            acc += bf2f(*(const unsigned short*)(h0 + off)) * wcls_lds[c * 256 + k];
        }
        acc += __shfl_xor(acc, 1);
        acc += __shfl_xor(acc, 2);
        if (q == 0) out[(size_t)(b0 + row) * 5 + c] = acc + bcls_lds[c];
    }
}

extern "C" void kernel_launch(void* const* d_in, const int* in_sizes, int n_in,
                              void* d_out, int out_size, void* d_ws, size_t ws_size,
                              hipStream_t stream)
{
    const int*   x     = (const int*)d_in[0];
    const float* emb   = (const float*)d_in[1];
    const float* W_ih  = (const float*)d_in[2];
    const float* W_hh  = (const float*)d_in[3];
    const float* b_ih  = (const float*)d_in[4];
    const float* b_hh  = (const float*)d_in[5];
    const float* W_cls = (const float*)d_in[6];
    const float* b_cls = (const float*)d_in[7];
    float*       out   = (float*)d_out;
    (void)d_ws; (void)ws_size;

    rnn_fused_kernel<<<256, 512, 0, stream>>>(x, emb, W_ih, W_hh,
                                              b_ih, b_hh, W_cls, b_cls, out);
}

// Round 16
// 222.330 us; speedup vs baseline: 1.1430x; 1.1430x over previous
//
#include <hip/hip_runtime.h>

// emb lookup -> RNN tanh(xp_t + h @ W_hh^T) over S=128 -> 5-class head.
// B=4096, S=128, D=256, VOCAB=50000. Floats f32, x int32, out f32.
//
// R22: revert to the banked best (R14, 222.78us; structure of R10/R11 ~222.3).
// Session ledger (R15 post-mortem): bench = kernel-time + ~68us FIXED harness
// overhead (R12: 294+71; R15-coop: 198+96; R15-RMW: 186+68=254). Two-kernel
// kernel-total is a CONSTANT 154.4us (emb ~14-24 + rnn ~130-140, split
// jitters). Composite floor = 68 (harness) + ~16 (emb, at 77MB streaming
// roofline) + ~130-138 (rnn, 113MB L2-miss gathers at the ~880GB/s
// random-512B-row ceiling that survived every perturbation) ~= 214-226.
// The fused kernel is in-device SLOWER (186 > 154) and still pays the 68 —
// fusion closed on the merits. This two-kernel form is the measured optimum.
//
// Phase 0: 512 thr (8 waves x 2 col-tiles), grid 256, double-buffered tin,
//   2-tile register prefetch, lgkm-only barriers, tout-staged FULL-LINE
//   uint4 g_P stores (R10: scattered 2B stores cost rnn ~10us via
//   partial-line writeback drain).
// Phase 1: R6 rnn (best measured 129.6-130.5us): depth-4 gather pipeline
//   (gA..gD), lgkm-only barriers, granule-XOR-swizzled h LDS, VGPR=100.

typedef __attribute__((ext_vector_type(8))) short bf16x8;   // 8 bf16 = 4 VGPRs
typedef __attribute__((ext_vector_type(4))) float f32x4;    // MFMA 16x16 accumulator

#define VOCAB 50000
#define LDS_STRIDE 264   // phase-0 staging stride (ushorts)

__device__ __align__(256) unsigned short g_P[VOCAB * 256];  // 25.6 MB projected table

static __device__ __forceinline__ float bf2f(unsigned short u) {
    union { unsigned int i; float f; } v; v.i = ((unsigned int)u) << 16; return v.f;
}
static __device__ __forceinline__ float bfbits2f(unsigned int zext_u16) {
    union { unsigned int i; float f; } v; v.i = zext_u16 << 16; return v.f;
}
static __device__ __forceinline__ unsigned short f2bf_rne(float f) {
    union { float f; unsigned int i; } v; v.f = f;
    unsigned int r = v.i + 0x7FFFu + ((v.i >> 16) & 1u);
    return (unsigned short)(r >> 16);
}
static __device__ __forceinline__ unsigned short f2bf_fast(float f) {   // round-half-up
    union { float f; unsigned int i; } v; v.f = f;
    return (unsigned short)((v.i + 0x8000u) >> 16);
}
static __device__ __forceinline__ bf16x8 cvt8(float4 a, float4 b) {
    bf16x8 r;
    r[0] = (short)f2bf_rne(a.x); r[1] = (short)f2bf_rne(a.y);
    r[2] = (short)f2bf_rne(a.z); r[3] = (short)f2bf_rne(a.w);
    r[4] = (short)f2bf_rne(b.x); r[5] = (short)f2bf_rne(b.y);
    r[6] = (short)f2bf_rne(b.z); r[7] = (short)f2bf_rne(b.w);
    return r;
}
static __device__ __forceinline__ bf16x8 load8_bf(const float* __restrict__ p) {
    return cvt8(((const float4*)p)[0], ((const float4*)p)[1]);
}
// tanh(x) = 1 - 2/(e^{2x}+1); med3 clamp keeps exp finite
static __device__ __forceinline__ float fast_tanh(float x) {
    x = __builtin_amdgcn_fmed3f(x, -8.f, 8.f);
    float e = __expf(2.f * x);
    return __builtin_fmaf(-2.f, __builtin_amdgcn_rcpf(e + 1.f), 1.f);
}
// Workgroup barrier that does NOT drain vmcnt: only LDS ops must be visible.
static __device__ __forceinline__ void barrier_lds_only() {
    asm volatile("s_waitcnt lgkmcnt(0)\n\ts_barrier" ::: "memory");
}

// ---------------- Phase 0: P = bf16(emb @ W_ih^T + (b_ih + b_hh)) ----------------
// 256 blocks x 512 thr (8 waves x 2 col-tiles). Tiles b, b+256, ... (13 max).
// Hazards: tin[i&1] written pre-B1(i), read post-B1(i); overwritten at i+2
// after all waves passed B1(i+1) > their reads. tout written pre-B2(i), read
// (for store) post-B2(i); rewritten at i+1 only after all waves passed
// B1(i+1), whose lgkmcnt(0) drains the tout reads.
__global__ __launch_bounds__(512)
void emb_proj_kernel(const float* __restrict__ emb,
                     const float* __restrict__ W_ih,
                     const float* __restrict__ b_ih,
                     const float* __restrict__ b_hh)
{
    __shared__ __align__(16) unsigned short tin[2][16 * LDS_STRIDE];
    __shared__ __align__(16) unsigned short tout[16 * LDS_STRIDE];
    const int tid  = threadIdx.x;
    const int lane = tid & 63;
    const int wid  = tid >> 6;          // 8 waves
    const int b    = blockIdx.x;
    const int n0   = wid * 32;          // wave's 32-col slice
    const int l15  = lane & 15;
    const int quad = lane >> 4;

    bf16x8 wfA[2][8];
    float  biasA[2];
    #pragma unroll
    for (int nt = 0; nt < 2; ++nt) {
        int n = n0 + nt * 16 + l15;
        biasA[nt] = b_ih[n] + b_hh[n];
        #pragma unroll
        for (int kt = 0; kt < 8; ++kt)
            wfA[nt][kt] = load8_bf(W_ih + n * 256 + quad * 8 + kt * 32);
    }

    const int srow = tid >> 5, sseg = tid & 31;   // staging map: 16 rows x 32 segs x 8 elems
    float4 p0a, p0b, p1a, p1b;                     // 2-tile register prefetch (static names)
    {
        const float4* s0 = (const float4*)(emb + ((size_t)b * 16 + srow) * 256 + sseg * 8);
        p0a = s0[0]; p0b = s0[1];
        int t1 = b + 256;
        if (t1 < 3125) {
            const float4* s1 = (const float4*)(emb + ((size_t)t1 * 16 + srow) * 256 + sseg * 8);
            p1a = s1[0]; p1b = s1[1];
        }
    }

    #define PROJ_STEP(I, PA, PB, TBUF)                                                 \
    {                                                                                  \
        int tile = b + (I) * 256;                                                      \
        if (tile < 3125) {                                                             \
            *(bf16x8*)(&TBUF[srow * LDS_STRIDE + sseg * 8]) = cvt8(PA, PB);            \
            int tf = tile + 512;                                                       \
            if (tf < 3125) {                                                           \
                const float4* s = (const float4*)(emb + ((size_t)tf * 16 + srow) * 256 + sseg * 8); \
                PA = s[0]; PB = s[1];                                                  \
            }                                                                          \
            barrier_lds_only();   /* B1: tin visible; prior tout reads drained */      \
            f32x4 acc0 = (f32x4){0.f, 0.f, 0.f, 0.f};                                  \
            f32x4 acc1 = (f32x4){0.f, 0.f, 0.f, 0.f};                                  \
            _Pragma("unroll")                                                          \
            for (int kt = 0; kt < 8; ++kt) {                                           \
                bf16x8 a = *(bf16x8*)(&TBUF[l15 * LDS_STRIDE + quad * 8 + kt * 32]);   \
                acc0 = __builtin_amdgcn_mfma_f32_16x16x32_bf16(a, wfA[0][kt], acc0, 0, 0, 0); \
                acc1 = __builtin_amdgcn_mfma_f32_16x16x32_bf16(a, wfA[1][kt], acc1, 0, 0, 0); \
            }                                                                          \
            _Pragma("unroll")                                                          \
            for (int r = 0; r < 4; ++r) {                                              \
                tout[(quad * 4 + r) * LDS_STRIDE + n0 + l15]      = f2bf_rne(acc0[r] + biasA[0]); \
                tout[(quad * 4 + r) * LDS_STRIDE + n0 + 16 + l15] = f2bf_rne(acc1[r] + biasA[1]); \
            }                                                                          \
            barrier_lds_only();   /* B2: tout complete */                              \
            uint4 o = *(uint4*)(&tout[srow * LDS_STRIDE + sseg * 8]);                  \
            *(uint4*)(g_P + ((size_t)tile * 16 + srow) * 256 + sseg * 8) = o;          \
        }                                                                              \
    }

    #pragma unroll 1
    for (int i2 = 0; i2 < 7; ++i2) {
        PROJ_STEP(2 * i2,     p0a, p0b, tin[0]);
        PROJ_STEP(2 * i2 + 1, p1a, p1b, tin[1]);
    }
    #undef PROJ_STEP
}

// ---------------- Phase 1: recurrence + classifier (R6 best, 129.6-130.5us) ----------------
// h LDS layout (per 8KB buffer): element (row m, col c) at byte
//   m*512 + (((c>>3) ^ m) << 4) + (c&7)*2      (granule-XOR swizzle, conflict-free writes)
__global__ __launch_bounds__(512, 2)
void rnn_kernel(const int* __restrict__ x,
                const float* __restrict__ W_hh,
                const float* __restrict__ W_cls,
                const float* __restrict__ b_cls,
                float* __restrict__ out)
{
    __shared__ __align__(16) unsigned short h_lds[2][16 * 256];  // 2 x 8 KB
    __shared__ __align__(16) int tok_t[128 * 16];                // [t][row]
    __shared__ __align__(16) float wcls_lds[5 * 256];
    __shared__ float bcls_lds[5];

    const int tid  = threadIdx.x;
    const int lane = tid & 63;
    const int wid  = tid >> 6;          // 8 waves
    const int b0   = blockIdx.x * 16;
    const int n0   = wid * 32;          // wave's 32-col slice
    const int l15  = lane & 15;
    const int quad = lane >> 4;

    // W_hh -> bf16 B-fragments, VGPR-resident
    bf16x8 wf[2][8];
    #pragma unroll
    for (int nt = 0; nt < 2; ++nt) {
        int n = n0 + nt * 16 + l15;
        #pragma unroll
        for (int kt = 0; kt < 8; ++kt)
            wf[nt][kt] = load8_bf(W_hh + n * 256 + quad * 8 + kt * 32);
    }

    // stage tokens transposed: tok_t[t*16 + row]
    {
        int row = tid & 15, tq = tid >> 4;   // tq 0..31
        int4 v = *(const int4*)(x + (size_t)(b0 + row) * 128 + tq * 4);
        tok_t[(tq * 4 + 0) * 16 + row] = v.x;
        tok_t[(tq * 4 + 1) * 16 + row] = v.y;
        tok_t[(tq * 4 + 2) * 16 + row] = v.z;
        tok_t[(tq * 4 + 3) * 16 + row] = v.w;
    }
    if (tid < 320) ((float4*)wcls_lds)[tid] = ((const float4*)W_cls)[tid];
    if (tid < 5)   bcls_lds[tid] = b_cls[tid];
    #pragma unroll
    for (int i = 0; i < 4; ++i) ((unsigned int*)h_lds[0])[tid + i * 512] = 0;

    // precomputed LDS byte offsets (loop-invariant; buf1 = +8192 imm)
    int aoff[8];
    #pragma unroll
    for (int kt = 0; kt < 8; ++kt)
        aoff[kt] = l15 * 512 + (((quad + 4 * kt) ^ l15) << 4);
    int woff[8];   // [nt*4 + r]
    #pragma unroll
    for (int nt = 0; nt < 2; ++nt)
        #pragma unroll
        for (int r = 0; r < 4; ++r) {
            int row = quad * 4 + r;
            int g   = (n0 >> 3) + nt * 2 + (l15 >> 3);
            woff[nt * 4 + r] = row * 512 + ((g ^ row) << 4) + (l15 & 7) * 2;
        }

    const unsigned int colByte = (unsigned int)(n0 + l15) * 2;   // within a g_P row

    // prologue: gather xp(t=0..3) -> gA..gD (4-step-deep pipeline; in-flight
    // gathers survive lgkm-only barriers, counted vmcnt at use)
    unsigned int gA[8], gB[8], gC[8], gD[8];
    #pragma unroll
    for (int r = 0; r < 4; ++r) {
        const int* xr = x + (size_t)(b0 + quad * 4 + r) * 128;
        const unsigned short* p0 = g_P + (size_t)xr[0] * 256 + n0 + l15;
        const unsigned short* p1 = g_P + (size_t)xr[1] * 256 + n0 + l15;
        const unsigned short* p2 = g_P + (size_t)xr[2] * 256 + n0 + l15;
        const unsigned short* p3 = g_P + (size_t)xr[3] * 256 + n0 + l15;
        gA[r] = p0[0]; gA[4 + r] = p0[16];
        gB[r] = p1[0]; gB[4 + r] = p1[16];
        gC[r] = p2[0]; gC[4 + r] = p2[16];
        gD[r] = p3[0]; gD[4 + r] = p3[16];
    }
    barrier_lds_only();

    char* const h0 = (char*)&h_lds[0][0];

    auto step = [&](const char* hA, char* hW, unsigned int* g, int t) {
        // consume g as MFMA C operand (xp pre-added for free)
        f32x4 acc0 = { bfbits2f(g[0]), bfbits2f(g[1]), bfbits2f(g[2]), bfbits2f(g[3]) };
        f32x4 acc1 = { bfbits2f(g[4]), bfbits2f(g[5]), bfbits2f(g[6]), bfbits2f(g[7]) };
        // refill g for t+4 (in flight across 4 barriers)
        if (t + 4 < 128) {
            int4 tk = *(const int4*)&tok_t[(t + 4) * 16 + quad * 4];
            const unsigned short* r0 = (const unsigned short*)((const char*)g_P + ((unsigned int)tk.x * 512 + colByte));
            const unsigned short* r1 = (const unsigned short*)((const char*)g_P + ((unsigned int)tk.y * 512 + colByte));
            const unsigned short* r2 = (const unsigned short*)((const char*)g_P + ((unsigned int)tk.z * 512 + colByte));
            const unsigned short* r3 = (const unsigned short*)((const char*)g_P + ((unsigned int)tk.w * 512 + colByte));
            g[0] = r0[0]; g[4] = r0[16];
            g[1] = r1[0]; g[5] = r1[16];
            g[2] = r2[0]; g[6] = r2[16];
            g[3] = r3[0]; g[7] = r3[16];
        }
        #pragma unroll
        for (int kt = 0; kt < 8; ++kt) {
            bf16x8 a = *(const bf16x8*)(hA + aoff[kt]);
            acc0 = __builtin_amdgcn_mfma_f32_16x16x32_bf16(a, wf[0][kt], acc0, 0, 0, 0);
            acc1 = __builtin_amdgcn_mfma_f32_16x16x32_bf16(a, wf[1][kt], acc1, 0, 0, 0);
        }
        #pragma unroll
        for (int r = 0; r < 4; ++r) {
            *(unsigned short*)(hW + woff[r])     = f2bf_fast(fast_tanh(acc0[r]));
            *(unsigned short*)(hW + woff[4 + r]) = f2bf_fast(fast_tanh(acc1[r]));
        }
    };

    #pragma unroll 1
    for (int t4 = 0; t4 < 32; ++t4) {
        step(h0,        h0 + 8192, gA, 4 * t4);
        barrier_lds_only();
        step(h0 + 8192, h0,        gB, 4 * t4 + 1);
        barrier_lds_only();
        step(h0,        h0 + 8192, gC, 4 * t4 + 2);
        barrier_lds_only();
        step(h0 + 8192, h0,        gD, 4 * t4 + 3);
        barrier_lds_only();
    }

    // final h in buf0 (step 127 wrote buf0). Classifier: 4 threads per (row,c).
    if (tid < 320) {
        int q = tid & 3, p = tid >> 2;
        int row = p / 5, c = p - row * 5;
        float acc = 0.f;
        #pragma unroll
        for (int kk = 0; kk < 64; ++kk) {
            int k = q * 64 + kk;
            int off = row * 512 + ((((k >> 3) ^ row)) << 4) + (k & 7) * 2;
            acc += bf2f(*(const unsigned short*)(h0 + off)) * wcls_lds[c * 256 + k];
        }
        acc += __shfl_xor(acc, 1);
        acc += __shfl_xor(acc, 2);
        if (q == 0) out[(size_t)(b0 + row) * 5 + c] = acc + bcls_lds[c];
    }
}

extern "C" void kernel_launch(void* const* d_in, const int* in_sizes, int n_in,
                              void* d_out, int out_size, void* d_ws, size_t ws_size,
                              hipStream_t stream)
{
    const int*   x     = (const int*)d_in[0];
    const float* emb   = (const float*)d_in[1];
    const float* W_ih  = (const float*)d_in[2];
    const float* W_hh  = (const float*)d_in[3];
    const float* b_ih  = (const float*)d_in[4];
    const float* b_hh  = (const float*)d_in[5];
    const float* W_cls = (const float*)d_in[6];
    const float* b_cls = (const float*)d_in[7];
    float*       out   = (float*)d_out;
    (void)d_ws; (void)ws_size;

    emb_proj_kernel<<<256, 512, 0, stream>>>(emb, W_ih, b_ih, b_hh);
    rnn_kernel<<<256, 512, 0, stream>>>(x, W_hh, W_cls, b_cls, out);
}